// Round 16
// baseline (31.104 us; speedup 1.0000x reference)
//
#include <hip/hip_runtime.h>
#include <hip/hip_bf16.h>
#include <math.h>

#define B_   2
#define N_   512
#define FN   128
#define FE   16
#define MID_ 128

typedef __attribute__((ext_vector_type(8)))  short short8_t;
typedef __attribute__((ext_vector_type(16))) float f32x16;

__device__ __forceinline__ short f2bf(float f) {
    __bf16 h = (__bf16)f;                    // fptrunc -> RNE bf16
    return __builtin_bit_cast(short, h);
}

// ---------------------------------------------------------------------------
// kA: three feat@W GEMMs as one-wave 32x32 MFMA tiles (8 K-steps of 16).
// grid 386 x 64 thr (byte-identical to round 10 — validated champion).
// ---------------------------------------------------------------------------
__global__ __launch_bounds__(64) void kA(
    const float* __restrict__ feat, const float* __restrict__ gfeat,
    const float* __restrict__ W1, const float* __restrict__ b1,
    const float* __restrict__ W2, const float* __restrict__ be,
    const float* __restrict__ Wg, const float* __restrict__ bg,
    const float* __restrict__ Wo1,
    float* __restrict__ msg1c, float* __restrict__ msg2, float* __restrict__ h1,
    float* __restrict__ msgg)
{
    const int bid = blockIdx.x;
    const int t   = threadIdx.x;

    if (bid >= 384) {            // ---- msgg blocks (one per b) ----
        const int b = bid - 384;
        const float* gb = gfeat + b * FN;
        #pragma unroll
        for (int half = 0; half < 2; ++half) {
            const int m = t + 64 * half;
            float mg = b1[m] + be[m] + bg[m];
            for (int k0 = 0; k0 < FN; k0 += 16) {
                float wv[16];
                #pragma unroll
                for (int u = 0; u < 16; ++u) wv[u] = Wg[(k0 + u) * MID_ + m];
                #pragma unroll
                for (int u = 0; u < 16; ++u) mg += gb[k0 + u] * wv[u];
            }
            msgg[b * MID_ + m] = mg;
        }
        return;
    }

    // ---- GEMM tile blocks ----
    const int bb  = bid / 192;               // batch
    const int rem = bid - bb * 192;
    const int nt  = rem / 12;                // row tile (32 rows)
    const int ct  = rem - nt * 12;           // 0..11
    const int w   = ct >> 2;                 // which W
    const int c0  = (ct & 3) * 32;           // col base
    const int n0  = nt * 32;
    const int g   = t >> 5, lm = t & 31;

    const float* Ws  = (w == 0) ? W1    : (w == 1) ? W2   : Wo1;
    float*       dst = (w == 0) ? msg1c : (w == 1) ? msg2 : h1;

    short8_t Af[8];
    #pragma unroll
    for (int ks = 0; ks < 8; ++ks) {
        const float* ap = feat + (size_t)(bb * N_ + n0 + lm) * FN + ks * 16 + 8 * g;
        const float4 a0 = *(const float4*)ap;
        const float4 a1 = *(const float4*)(ap + 4);
        short8_t A;
        A[0] = f2bf(a0.x); A[1] = f2bf(a0.y); A[2] = f2bf(a0.z); A[3] = f2bf(a0.w);
        A[4] = f2bf(a1.x); A[5] = f2bf(a1.y); A[6] = f2bf(a1.z); A[7] = f2bf(a1.w);
        Af[ks] = A;
    }
    short8_t Bfr[8];
    #pragma unroll
    for (int ks = 0; ks < 8; ++ks) {
        short8_t Bv;
        #pragma unroll
        for (int j = 0; j < 8; ++j)
            Bv[j] = f2bf(Ws[(size_t)(ks * 16 + 8 * g + j) * MID_ + c0 + lm]);
        Bfr[ks] = Bv;
    }

    f32x16 acc;
    #pragma unroll
    for (int r = 0; r < 16; ++r) acc[r] = 0.0f;
    #pragma unroll
    for (int ks = 0; ks < 8; ++ks)
        acc = __builtin_amdgcn_mfma_f32_32x32x16_bf16(Af[ks], Bfr[ks], acc, 0, 0, 0);

    #pragma unroll
    for (int r = 0; r < 16; ++r) {
        const int row = (r & 3) + 8 * (r >> 2) + 4 * g;
        dst[(size_t)(bb * N_ + n0 + row) * MID_ + c0 + lm] = acc[r];
    }
}

// ---------------------------------------------------------------------------
// kB round 16: BARRIER-FREE 4-wave blocks.
// grid 1024 = 2b x 16jt x 32ic (16 i per chunk); block 256 = 4 waves = 4 mt.
// Each wave self-sufficient: own 16 adj ballots -> VGPR masks (redundant x4,
// L3-resident), andm 0-floor in-register, msg2/msg1c direct from global
// (L2-resident), fully-unrolled 16-i MFMA loop. NO __syncthreads, NO LDS,
// NO cross-wave merge (wave owns its 32 m cols). VGPR ~100 < 128 cap.
// (r13-r15 lesson: per-wave instruction mix is NOT the bottleneck; the
//  8-wave barrier-coupled 512-thr block structure is the last untested axis.)
// ---------------------------------------------------------------------------
__global__ __launch_bounds__(256, 4) void kB(
    const float* __restrict__ ef, const float* __restrict__ adj,
    const float* __restrict__ We, const float* __restrict__ b2,
    const float* __restrict__ msg1c, const float* __restrict__ msg2,
    const float* __restrict__ msgg,
    float* __restrict__ part)
{
    const int bid = blockIdx.x;            // 1024 = 2b * 16jt * 32ic
    const int b   = bid >> 9;
    const int jt  = (bid >> 5) & 15;
    const int ic  = bid & 31;
    const int j0  = jt * 32, i0 = ic * 16;
    const int t    = threadIdx.x;
    const int lane = t & 63, mt = t >> 6;  // 4 waves = 4 mt
    const int g    = lane >> 5, lm = lane & 31;

    // ---- adj ballots: 16 masks in VGPRs (2 i per ballot) ----
    unsigned m[16];
    #pragma unroll
    for (int p = 0; p < 8; ++p) {
        const int i_l = 2 * p + g;
        const float av = adj[(size_t)(b * N_ + i0 + i_l) * N_ + j0 + lm];
        const unsigned long long bal = __ballot(av != 0.0f);
        m[2 * p]     = (unsigned)bal;
        m[2 * p + 1] = (unsigned)(bal >> 32);
    }
    unsigned andm = 0xFFFFFFFFu;
    #pragma unroll
    for (int i = 0; i < 16; ++i) andm &= m[i];

    // B fragment: We[k=8g+jj, mt*32+lm]
    short8_t Bf;
    #pragma unroll
    for (int jj = 0; jj < 8; ++jj)
        Bf[jj] = f2bf(We[(8 * g + jj) * MID_ + mt * 32 + lm]);
    const float b2v = b2[mt * 32 + lm];

    f32x16 accm;
    #pragma unroll
    for (int r = 0; r < 16; ++r) accm[r] = -INFINITY;

    // ---- main loop: 16 i, fully unrolled (m[ii] register-indexed) ----
    const float* efr = ef + ((size_t)(b * N_ + i0) * N_ + j0 + lm) * FE + 8 * g;
    const float* m2p = msg2 + (size_t)(b * N_ + i0) * MID_ + mt * 32 + lm;
    #pragma unroll
    for (int ii = 0; ii < 16; ++ii) {
        const float4 ea = *(const float4*)efr;
        const float4 eb = *(const float4*)(efr + 4);
        efr += (size_t)N_ * FE;
        const float m2v = *m2p + b2v;
        m2p += MID_;
        short8_t Af;
        Af[0] = f2bf(ea.x); Af[1] = f2bf(ea.y); Af[2] = f2bf(ea.z); Af[3] = f2bf(ea.w);
        Af[4] = f2bf(eb.x); Af[5] = f2bf(eb.y); Af[6] = f2bf(eb.z); Af[7] = f2bf(eb.w);

        const unsigned vmg = m[ii] >> (4 * g);
        f32x16 C;
        #pragma unroll
        for (int r = 0; r < 16; ++r) {
            const int cr = (r & 3) + 8 * (r >> 2);
            C[r] = (vmg & (1u << cr)) ? m2v : -INFINITY;
        }
        const f32x16 S = __builtin_amdgcn_mfma_f32_32x32x16_bf16(Af, Bf, C, 0, 0, 0);
        #pragma unroll
        for (int r = 0; r < 16; ++r) accm[r] = fmaxf(accm[r], S[r]);
    }

    // ---- epilogue: +c1+msgg, 0-floor from andm, direct store ----
    const float ggv = msgg[b * MID_ + mt * 32 + lm];
    #pragma unroll
    for (int r = 0; r < 16; ++r) {
        const int jrow = (r & 3) + 8 * (r >> 2) + 4 * g;
        const float az = ((andm >> jrow) & 1u) ? -INFINITY : 0.0f;
        const float c1v = msg1c[(size_t)(b * N_ + j0 + jrow) * MID_ + mt * 32 + lm];
        const float v = fmaxf(accm[r] + c1v + ggv, az);
        part[((size_t)(ic * 2 + b) * N_ + j0 + jrow) * MID_ + mt * 32 + lm] = v;
    }
}

// ---------------------------------------------------------------------------
// kC: msgs = max over 32 f32 partials; out = (h1_raw + bo1) + msgs@Wo2 + bo2
// grid 512 = 2b x 256jt (2 rows); block 256 (r10 body, 32-chunk reduce)
// ---------------------------------------------------------------------------
__global__ __launch_bounds__(256, 2) void kC(
    const float* __restrict__ part, const float* __restrict__ h1,
    const float* __restrict__ Wo2, const float* __restrict__ bo1,
    const float* __restrict__ bo2,
    float* __restrict__ out)
{
    __shared__ float ms[2 * MID_];
    const int bid = blockIdx.x;          // 512 = 2b * 256 tiles
    const int b   = bid >> 8;
    const int j0  = (bid & 255) * 2;
    const int t   = threadIdx.x;
    const int r   = t >> 7, m = t & 127;
    const size_t base = ((size_t)b * N_ + j0 + r) * MID_ + m;

    float u = -INFINITY;
    #pragma unroll
    for (int icc = 0; icc < 32; ++icc)
        u = fmaxf(u, part[(size_t)icc * 2 * N_ * MID_ + base]);
    ms[r * MID_ + m] = u;
    __syncthreads();

    float acc = h1[base] + bo1[m] + bo2[m];
    for (int k0 = 0; k0 < MID_; k0 += 8) {
        float wv[8];
        #pragma unroll
        for (int uu = 0; uu < 8; ++uu) wv[uu] = Wo2[(k0 + uu) * MID_ + m];
        #pragma unroll
        for (int uu = 0; uu < 8; ++uu) acc += ms[r * MID_ + k0 + uu] * wv[uu];
    }
    out[base] = acc;
}

// ---------------------------------------------------------------------------
extern "C" void kernel_launch(void* const* d_in, const int* in_sizes, int n_in,
                              void* d_out, int out_size, void* d_ws, size_t ws_size,
                              hipStream_t stream)
{
    const float* feat = (const float*)d_in[0];
    const float* ef   = (const float*)d_in[1];
    const float* gf   = (const float*)d_in[2];
    const float* adj  = (const float*)d_in[3];
    const float* W1   = (const float*)d_in[4];
    const float* b1   = (const float*)d_in[5];
    const float* W2   = (const float*)d_in[6];
    const float* b2   = (const float*)d_in[7];
    const float* We   = (const float*)d_in[8];
    const float* be   = (const float*)d_in[9];
    const float* Wg   = (const float*)d_in[10];
    const float* bg   = (const float*)d_in[11];
    const float* Wo1  = (const float*)d_in[12];
    const float* bo1  = (const float*)d_in[13];
    const float* Wo2  = (const float*)d_in[14];
    const float* bo2  = (const float*)d_in[15];
    float* out = (float*)d_out;

    float* ws    = (float*)d_ws;
    float* msg1c = ws;                        // 131072 f32 (raw feat@W1)
    float* msg2  = ws + 131072;               // 131072 f32 (raw feat@W2)
    float* h1    = ws + 262144;               // 131072 f32 (raw feat@Wo1)
    float* part  = ws + 393216;               // 32ic*2b*512*128 f32 = 16 MB
    float* msgg  = ws + 393216 + 4194304;     // 256 f32

    hipLaunchKernelGGL(kA, dim3(386), dim3(64), 0, stream,
        feat, gf, W1, b1, W2, be, Wg, bg, Wo1, msg1c, msg2, h1, msgg);
    hipLaunchKernelGGL(kB, dim3(1024), dim3(256), 0, stream,
        ef, adj, We, b2, msg1c, msg2, msgg, part);
    hipLaunchKernelGGL(kC, dim3(512), dim3(256), 0, stream,
        part, h1, Wo2, bo1, bo2, out);
}